// Round 1
// baseline (88.243 us; speedup 1.0000x reference)
//
#include <hip/hip_runtime.h>
#include <hip/hip_bf16.h>

#define N_NODES 10000
#define IN_CH 128
#define HID 256
#define E_TAR 8192
#define N_EDGES 320000
#define WPR 320          // bitmask words per row (313 used, padded)
#define WUSED 313
#define MAXCN 256

typedef short bf16x8 __attribute__((ext_vector_type(8)));
typedef float f32x4 __attribute__((ext_vector_type(4)));

__device__ __forceinline__ unsigned short f2bf(float f) {
  union { float f; unsigned u; } v; v.f = f;
  unsigned r = v.u + 0x7fffu + ((v.u >> 16) & 1u);  // RNE
  return (unsigned short)(r >> 16);
}

__global__ void scatter_adj(const int* __restrict__ row, const int* __restrict__ col,
                            unsigned* __restrict__ mask) {
  int k = blockIdx.x * 256 + threadIdx.x;
  if (k < N_EDGES) {
    int r = row[k], c = col[k];
    atomicOr(&mask[(size_t)r * WPR + (c >> 5)], 1u << (c & 31));
  }
}

// one block (128 threads) per target edge: AND the two adjacency rows,
// list common neighbors in LDS, then channel-parallel feature sum.
__global__ void cn_gather(const unsigned* __restrict__ mask, const int* __restrict__ tar,
                          const float* __restrict__ x, float* __restrict__ cnx) {
  __shared__ int cnt;
  __shared__ int list[MAXCN];
  int e = blockIdx.x;
  int i = tar[e], j = tar[E_TAR + e];
  if (threadIdx.x == 0) cnt = 0;
  __syncthreads();
  const unsigned* mi = mask + (size_t)i * WPR;
  const unsigned* mj = mask + (size_t)j * WPR;
  for (int w = threadIdx.x; w < WUSED; w += 128) {
    unsigned v = mi[w] & mj[w];
    while (v) {
      int b = __ffs(v) - 1;
      v &= v - 1;
      int pos = atomicAdd(&cnt, 1);
      if (pos < MAXCN) list[pos] = w * 32 + b;
    }
  }
  __syncthreads();
  int n = cnt; if (n > MAXCN) n = MAXCN;
  int c = threadIdx.x;             // 128 threads == IN_CH channels
  float acc = 0.f;
  for (int t = 0; t < n; ++t) acc += x[(size_t)list[t] * IN_CH + c];
  cnx[(size_t)e * IN_CH + c] = acc;
}

// C[M,N] = f(A @ W + bias [+ scale*extra]); A is [M,K] f32, or fused xi*xj
// gather when tar != nullptr. W is [K,N] f32 row-major. bf16 MFMA 16x16x32.
// 64x64 tile, 256 threads = 4 waves in 2x2, BK=32.
__global__ __launch_bounds__(256) void gemm_mfma(
    const float* __restrict__ A, const float* __restrict__ W,
    const float* __restrict__ bias, const float* __restrict__ extra,
    const float* __restrict__ scalePtr, const int* __restrict__ tar,
    const float* __restrict__ x, int relu, int M, int N, int K,
    float* __restrict__ C)
{
  __shared__ unsigned short As[64][56];   // 112B row stride: 16B-aligned, ~2-way banks
  __shared__ unsigned short Bs[64][56];   // Bs[n][k] (W staged transposed)
  int m0 = blockIdx.x * 64;
  int n0 = blockIdx.y * 64;
  int tid = threadIdx.x;
  int lane = tid & 63, wv = tid >> 6;
  int wm0 = (wv >> 1) * 32, wn0 = (wv & 1) * 32;
  f32x4 acc[2][2] = {};

  int arow = tid >> 2, akb = (tid & 3) * 8;   // A staging: row arow, k akb..akb+7
  int bn = tid & 63, bkb = (tid >> 6) * 8;    // B staging: col bn, k bkb..bkb+7
  int gi = 0, gj = 0;
  if (tar) { gi = tar[m0 + arow]; gj = tar[E_TAR + m0 + arow]; }

  for (int k0 = 0; k0 < K; k0 += 32) {
    float av[8];
    if (tar) {
      const float* xi = x + (size_t)gi * IN_CH + k0 + akb;
      const float* xj = x + (size_t)gj * IN_CH + k0 + akb;
      #pragma unroll
      for (int u = 0; u < 8; ++u) av[u] = xi[u] * xj[u];
    } else {
      const float* ap = A + (size_t)(m0 + arow) * K + k0 + akb;
      #pragma unroll
      for (int u = 0; u < 8; ++u) av[u] = ap[u];
    }
    unsigned short abf[8];
    #pragma unroll
    for (int u = 0; u < 8; ++u) abf[u] = f2bf(av[u]);
    *(bf16x8*)&As[arow][akb] = *(bf16x8*)abf;

    unsigned short bbf[8];
    #pragma unroll
    for (int u = 0; u < 8; ++u) bbf[u] = f2bf(W[(size_t)(k0 + bkb + u) * N + n0 + bn]);
    *(bf16x8*)&Bs[bn][bkb] = *(bf16x8*)bbf;
    __syncthreads();

    int l15 = lane & 15, kq = (lane >> 4) * 8;
    bf16x8 a0 = *(bf16x8*)&As[wm0 + l15][kq];
    bf16x8 a1 = *(bf16x8*)&As[wm0 + 16 + l15][kq];
    bf16x8 b0 = *(bf16x8*)&Bs[wn0 + l15][kq];
    bf16x8 b1 = *(bf16x8*)&Bs[wn0 + 16 + l15][kq];
    acc[0][0] = __builtin_amdgcn_mfma_f32_16x16x32_bf16(a0, b0, acc[0][0], 0, 0, 0);
    acc[0][1] = __builtin_amdgcn_mfma_f32_16x16x32_bf16(a0, b1, acc[0][1], 0, 0, 0);
    acc[1][0] = __builtin_amdgcn_mfma_f32_16x16x32_bf16(a1, b0, acc[1][0], 0, 0, 0);
    acc[1][1] = __builtin_amdgcn_mfma_f32_16x16x32_bf16(a1, b1, acc[1][1], 0, 0, 0);
    __syncthreads();
  }

  float scale = scalePtr ? scalePtr[0] : 0.f;
  int l15 = lane & 15, rq = (lane >> 4) * 4;
  #pragma unroll
  for (int fm = 0; fm < 2; ++fm) {
    #pragma unroll
    for (int fn = 0; fn < 2; ++fn) {
      int cg = n0 + wn0 + fn * 16 + l15;
      float bv = bias[cg];
      #pragma unroll
      for (int i2 = 0; i2 < 4; ++i2) {
        int rg = m0 + wm0 + fm * 16 + rq + i2;
        float v = acc[fm][fn][i2] + bv;
        if (extra) v += scale * extra[(size_t)rg * N + cg];
        if (relu) v = fmaxf(v, 0.f);
        C[(size_t)rg * N + cg] = v;
      }
    }
  }
}

// out[row] = h[row,:] . Wl2 + bl2 ; one wave per row
__global__ void final_dot(const float* __restrict__ h, const float* __restrict__ w2,
                          const float* __restrict__ b2, float* __restrict__ out) {
  int wv = threadIdx.x >> 6, lane = threadIdx.x & 63;
  int row = blockIdx.x * 4 + wv;
  const float* hr = h + (size_t)row * HID;
  float s = 0.f;
  #pragma unroll
  for (int t = 0; t < 4; ++t) s += hr[lane + 64 * t] * w2[lane + 64 * t];
  #pragma unroll
  for (int off = 32; off; off >>= 1) s += __shfl_down(s, off);
  if (lane == 0) out[row] = s + b2[0];
}

extern "C" void kernel_launch(void* const* d_in, const int* in_sizes, int n_in,
                              void* d_out, int out_size, void* d_ws, size_t ws_size,
                              hipStream_t stream) {
  const float* x      = (const float*)d_in[0];
  const int*   adj_r  = (const int*)d_in[1];
  const int*   adj_c  = (const int*)d_in[2];
  const int*   tar    = (const int*)d_in[3];
  const float* beta   = (const float*)d_in[4];
  const float* W1     = (const float*)d_in[5];
  const float* b1     = (const float*)d_in[6];
  const float* W2     = (const float*)d_in[7];
  const float* b2     = (const float*)d_in[8];
  const float* W3     = (const float*)d_in[9];
  const float* b3     = (const float*)d_in[10];
  const float* Wij1   = (const float*)d_in[11];
  const float* bij1   = (const float*)d_in[12];
  const float* Wij2   = (const float*)d_in[13];
  const float* bij2   = (const float*)d_in[14];
  const float* Wl1    = (const float*)d_in[15];
  const float* bl1    = (const float*)d_in[16];
  const float* Wl2    = (const float*)d_in[17];
  const float* bl2    = (const float*)d_in[18];

  char* ws = (char*)d_ws;
  unsigned* mask = (unsigned*)ws;                          // 12.8 MB
  float* bufA = (float*)(ws + (size_t)16 * 1024 * 1024);   // 8 MB each
  float* bufB = (float*)(ws + (size_t)24 * 1024 * 1024);
  float* bufC = (float*)(ws + (size_t)32 * 1024 * 1024);

  hipMemsetAsync(mask, 0, (size_t)N_NODES * WPR * 4, stream);
  scatter_adj<<<(N_EDGES + 255) / 256, 256, 0, stream>>>(adj_r, adj_c, mask);
  cn_gather<<<E_TAR, 128, 0, stream>>>(mask, tar, x, bufA);

  dim3 g(E_TAR / 64, HID / 64);  // 128 x 4
  // t1 = relu(cn_x @ W1 + b1)
  gemm_mfma<<<g, 256, 0, stream>>>(bufA, W1, b1, nullptr, nullptr, nullptr, nullptr, 1, E_TAR, HID, IN_CH, bufB);
  // t2 = relu(t1 @ W2 + b2)
  gemm_mfma<<<g, 256, 0, stream>>>(bufB, W2, b2, nullptr, nullptr, nullptr, nullptr, 1, E_TAR, HID, HID, bufC);
  // xcn = t2 @ W3 + b3
  gemm_mfma<<<g, 256, 0, stream>>>(bufC, W3, b3, nullptr, nullptr, nullptr, nullptr, 0, E_TAR, HID, HID, bufB);
  // u1 = relu((xi*xj) @ Wij1 + bij1)   (fused gather-product A)
  gemm_mfma<<<g, 256, 0, stream>>>(nullptr, Wij1, bij1, nullptr, nullptr, tar, x, 1, E_TAR, HID, IN_CH, bufC);
  // v = (u1 @ Wij2 + bij2) + beta * xcn
  gemm_mfma<<<g, 256, 0, stream>>>(bufC, Wij2, bij2, bufB, beta, nullptr, nullptr, 0, E_TAR, HID, HID, bufA);
  // h = relu(v @ Wl1 + bl1)
  gemm_mfma<<<g, 256, 0, stream>>>(bufA, Wl1, bl1, nullptr, nullptr, nullptr, nullptr, 1, E_TAR, HID, HID, bufC);
  // out = h @ Wl2 + bl2
  final_dot<<<E_TAR / 4, 256, 0, stream>>>(bufC, Wl2, bl2, (float*)d_out);
}